// Round 10
// baseline (152.483 us; speedup 1.0000x reference)
//
#include <hip/hip_runtime.h>
#include <hip/hip_bf16.h>
#include <math.h>

#define N      8192
#define FIN    94
#define FOUT   16
#define ALPHA  0.2f
#define BM     16            // rows per block (main kernel)
#define WJ     1024          // j-columns per wave
#define NWAVE  8             // waves per block; NWAVE*WJ == N
#define NT_T   (WJ / 32)     // 32 col-tiles per wave

// ws layout: bf16 Wh_t[16][8192] at byte 0 (256 KB), then f32 tables.
#define AR_OFF 65536               // exp(s_src)
#define CR_OFF (AR_OFF + N)        // exp(0.2*s_src)
#define BX_OFF (AR_OFF + 2*N)      // exp(s_dst)
#define DX_OFF (AR_OFF + 3*N)      // exp(0.2*s_dst)

typedef int   i32x4 __attribute__((ext_vector_type(4)));
typedef float f32x4 __attribute__((ext_vector_type(4)));
typedef short s16x8 __attribute__((ext_vector_type(8)));

// Kernel 1: Wh (bf16, transposed) + four exp tables.
__global__ __launch_bounds__(256) void wh_score_kernel(
    const float* __restrict__ h, const float* __restrict__ W,
    const float* __restrict__ attn, float* __restrict__ ws)
{
    const int gid = blockIdx.x * 256 + threadIdx.x;  // 0..131071
    const int i = gid >> 4;
    const int k = gid & 15;
    const float* hrow = h + i * FIN;
    float a0 = 0.f, a1 = 0.f, a2 = 0.f, a3 = 0.f;
    #pragma unroll
    for (int c = 0; c < 92; c += 4) {
        a0 = fmaf(hrow[c],     W[c * FOUT + k],       a0);
        a1 = fmaf(hrow[c + 1], W[(c + 1) * FOUT + k], a1);
        a2 = fmaf(hrow[c + 2], W[(c + 2) * FOUT + k], a2);
        a3 = fmaf(hrow[c + 3], W[(c + 3) * FOUT + k], a3);
    }
    a0 = fmaf(hrow[92], W[92 * FOUT + k], a0);
    a1 = fmaf(hrow[93], W[93 * FOUT + k], a1);
    const float acc = (a0 + a1) + (a2 + a3);

    __hip_bfloat16* whtb = (__hip_bfloat16*)ws;
    whtb[k * N + i] = __float2bfloat16(acc);   // transposed bf16 store

    float ps = acc * attn[k];
    float pd = acc * attn[FOUT + k];
    #pragma unroll
    for (int mk = 1; mk < 16; mk <<= 1) {
        ps += __shfl_xor(ps, mk);
        pd += __shfl_xor(pd, mk);
    }
    if (k == 0) {
        // |scores| small: exp() safe in f32, softmax shift-invariant -> no max pass.
        ws[AR_OFF + i] = __expf(ps);
        ws[CR_OFF + i] = __expf(ALPHA * ps);
        ws[BX_OFF + i] = __expf(pd);
        ws[DX_OFF + i] = __expf(ALPHA * pd);
    }
}

// Kernel 2 (main): MFMA masked-softmax-weighted accumulation.
// Block = 512 threads / 8 waves sharing 16 output rows; per-wave disjoint
// 1024-col j-slice; depth-4 register ring; in-block reduce + ELU.
// IDEMPOTENT (reads adj+ws, overwrites out) -> relaunchable for timing.
__global__ __launch_bounds__(512, 4) void gat_mfma_kernel(
    const int* __restrict__ adj, const float* __restrict__ ws,
    float* __restrict__ out)
{
    __shared__ float smem[16384];

    const int tid = threadIdx.x;     // 0..511
    const int i0 = blockIdx.x * BM;  // 16 rows per block

    #pragma unroll
    for (int u = 0; u < 4; ++u) {
        const int idx = u * 2048 + tid * 4;
        *(f32x4*)(smem + idx)        = *(const f32x4*)(ws + BX_OFF + idx);
        *(f32x4*)(smem + 8192 + idx) = *(const f32x4*)(ws + DX_OFF + idx);
    }
    __syncthreads();

    const int w    = tid >> 6;    // wave id = j-slice id
    const int lane = tid & 63;
    const int c15  = lane & 15;   // A-row (local), B-col, C-col
    const int g    = lane >> 4;   // k-group: this lane covers k = 8g..8g+7
    const int arow = i0 + c15;
    const int jc0  = w * WJ;

    const float Ar = ws[AR_OFF + arow];
    const float Cr = ws[CR_OFF + arow];

    const float* __restrict__ Bl = smem + jc0;
    const float* __restrict__ Dl = smem + 8192 + jc0;
    const unsigned short* __restrict__ whtb = (const unsigned short*)ws;
    const int* __restrict__ ap            = adj + (size_t)arow * N + jc0 + 8 * g;
    const unsigned short* __restrict__ wp = whtb + c15 * N + jc0 + 8 * g;

    f32x4 acc = {0.f, 0.f, 0.f, 0.f};
    float lsum = 0.f;

    i32x4 a0_0, a1_0, a0_1, a1_1, a0_2, a1_2, a0_3, a1_3;
    s16x8 fb_0, fb_1, fb_2, fb_3;

#define ISSUE(s, t) do {                                                       \
    const int off_ = 32 * (t);                                                 \
    a0_##s = *(const i32x4*)(ap + off_);                                       \
    a1_##s = *(const i32x4*)(ap + off_ + 4);                                   \
    fb_##s = *(const s16x8*)(wp + off_);                                       \
} while (0)

#define COMPUTE(s, t) do {                                                     \
    const int lb = (t) * 32 + 8 * g;                                           \
    const f32x4 B0 = *(const f32x4*)(Bl + lb);                                 \
    const f32x4 B1 = *(const f32x4*)(Bl + lb + 4);                             \
    const f32x4 D0 = *(const f32x4*)(Dl + lb);                                 \
    const f32x4 D1 = *(const f32x4*)(Dl + lb + 4);                             \
    float wf[8];                                                               \
    _Pragma("unroll") for (int e = 0; e < 4; ++e) {                            \
        const float ww = (a0_##s[e] > 0) ?                                     \
            fmaxf(Ar * B0[e], Cr * D0[e]) : 0.0f;                              \
        wf[e] = ww; lsum += ww;                                                \
    }                                                                          \
    _Pragma("unroll") for (int e = 0; e < 4; ++e) {                            \
        const float ww = (a1_##s[e] > 0) ?                                     \
            fmaxf(Ar * B1[e], Cr * D1[e]) : 0.0f;                              \
        wf[4 + e] = ww; lsum += ww;                                            \
    }                                                                          \
    s16x8 fa;                                                                  \
    _Pragma("unroll") for (int e = 0; e < 8; ++e)                              \
        fa[e] = (short)__builtin_bit_cast(unsigned short,                      \
                                          __float2bfloat16(wf[e]));           \
    acc = __builtin_amdgcn_mfma_f32_16x16x32_bf16(fa, fb_##s, acc, 0, 0, 0);   \
} while (0)

    ISSUE(0, 0); ISSUE(1, 1); ISSUE(2, 2); ISSUE(3, 3);

    #pragma unroll 1
    for (int t = 0; t < NT_T - 4; t += 4) {
        COMPUTE(0, t);     ISSUE(0, t + 4);
        COMPUTE(1, t + 1); ISSUE(1, t + 5);
        COMPUTE(2, t + 2); ISSUE(2, t + 6);
        COMPUTE(3, t + 3); ISSUE(3, t + 7);
    }
    COMPUTE(0, NT_T - 4); COMPUTE(1, NT_T - 3);
    COMPUTE(2, NT_T - 2); COMPUTE(3, NT_T - 1);
#undef ISSUE
#undef COMPUTE

    lsum += __shfl_xor(lsum, 16);
    lsum += __shfl_xor(lsum, 32);

    __syncthreads();
    #pragma unroll
    for (int r = 0; r < 4; ++r)
        smem[(w * 64 + lane) * 4 + r] = acc[r];
    if (g == 0)
        smem[2048 + w * 16 + c15] = lsum;
    __syncthreads();

    if (w == 0) {
        // C/D layout (m89-verified): col = lane&15, row = (lane>>4)*4 + reg
        float tot[4] = {0.f, 0.f, 0.f, 0.f};
        float den[4] = {0.f, 0.f, 0.f, 0.f};
        #pragma unroll
        for (int ww = 0; ww < NWAVE; ++ww) {
            #pragma unroll
            for (int r = 0; r < 4; ++r) {
                tot[r] += smem[(ww * 64 + lane) * 4 + r];
                den[r] += smem[2048 + ww * 16 + (4 * g + r)];
            }
        }
        #pragma unroll
        for (int r = 0; r < 4; ++r) {
            const float v = tot[r] / den[r];
            out[(i0 + 4 * g + r) * FOUT + c15] =
                (v > 0.0f) ? v : expm1f(v);   // ELU
        }
    }
}

extern "C" void kernel_launch(void* const* d_in, const int* in_sizes, int n_in,
                              void* d_out, int out_size, void* d_ws, size_t ws_size,
                              hipStream_t stream)
{
    const float* h    = (const float*)d_in[0];
    const int*   adj  = (const int*)d_in[1];
    const float* W    = (const float*)d_in[2];
    const float* attn = (const float*)d_in[3];
    float* out = (float*)d_out;
    float* ws  = (float*)d_ws;

    wh_score_kernel<<<(N * FOUT) / 256, 256, 0, stream>>>(h, W, attn, ws);
    // MEASUREMENT ROUND: main launched 3x (idempotent -> identical output).
    // Delta vs round 9's 59.3us = 2*(gap + M_warm); copies 2&3 run with adj
    // fully L3-resident.  M_warm ~25 => memory-sensitive branch; ~50 =>
    // machinery-bound branch.
    gat_mfma_kernel<<<N / BM, 512, 0, stream>>>(adj, ws, out);
    gat_mfma_kernel<<<N / BM, 512, 0, stream>>>(adj, ws, out);
    gat_mfma_kernel<<<N / BM, 512, 0, stream>>>(adj, ws, out);
}

// Round 11
// 59.374 us; speedup vs baseline: 2.5682x; 2.5682x over previous
//
#include <hip/hip_runtime.h>
#include <hip/hip_bf16.h>
#include <math.h>

#define N      8192
#define FIN    94
#define FOUT   16
#define ALPHA  0.2f
#define BM     16            // rows per block (main kernel)
#define WJ     1024          // j-columns per wave
#define NWAVE  8             // waves per block; NWAVE*WJ == N
#define NT_T   (WJ / 32)     // 32 col-tiles per wave
#define RPRO   32            // rows per prologue block

// ws layout: bf16 Wh_t[16][8192] at byte 0 (256 KB), then f32 tables.
#define AR_OFF 65536               // exp(s_src)
#define CR_OFF (AR_OFF + N)        // exp(0.2*s_src)
#define BX_OFF (AR_OFF + 2*N)      // exp(s_dst)
#define DX_OFF (AR_OFF + 3*N)      // exp(0.2*s_dst)

typedef int   i32x4 __attribute__((ext_vector_type(4)));
typedef float f32x4 __attribute__((ext_vector_type(4)));
typedef short s16x8 __attribute__((ext_vector_type(8)));

// Kernel 1 (prologue): Wh (bf16, transposed) + four exp tables.
// Block = 256 threads, 32 rows: h rows staged into LDS with coalesced
// f32x4 loads (kills the old 16x-redundant scalar global reads), then
// thread (r,k) computes dot(h_r, W[:,k]) from LDS broadcasts.
__global__ __launch_bounds__(256) void wh_score_kernel(
    const float* __restrict__ h, const float* __restrict__ W,
    const float* __restrict__ attn, float* __restrict__ ws)
{
    __shared__ float hl[RPRO * FIN];     // 32*94 = 3008 floats = 12 KB

    const int tid = threadIdx.x;
    const int i0 = blockIdx.x * RPRO;

    // stage: contiguous range h[i0*94 .. i0*94+3008), 16B-aligned (3008%4==0)
    const float* hsrc = h + i0 * FIN;
    #pragma unroll
    for (int u = 0; u < 3; ++u) {
        const int idx = (u * 256 + tid) * 4;
        if (idx < RPRO * FIN)
            *(f32x4*)(hl + idx) = *(const f32x4*)(hsrc + idx);
    }
    __syncthreads();

    const int k  = tid & 15;
    const int rr = tid >> 4;             // 0..15
    const float wa1 = attn[k];
    const float wa2 = attn[FOUT + k];
    __hip_bfloat16* whtb = (__hip_bfloat16*)ws;

    #pragma unroll
    for (int half = 0; half < 2; ++half) {
        const int r = rr + 16 * half;    // local row 0..31
        const float* hrow = hl + r * FIN;
        float a0 = 0.f, a1 = 0.f, a2 = 0.f, a3 = 0.f;
        #pragma unroll
        for (int c = 0; c < 92; c += 4) {
            a0 = fmaf(hrow[c],     W[c * FOUT + k],       a0);
            a1 = fmaf(hrow[c + 1], W[(c + 1) * FOUT + k], a1);
            a2 = fmaf(hrow[c + 2], W[(c + 2) * FOUT + k], a2);
            a3 = fmaf(hrow[c + 3], W[(c + 3) * FOUT + k], a3);
        }
        a0 = fmaf(hrow[92], W[92 * FOUT + k], a0);
        a1 = fmaf(hrow[93], W[93 * FOUT + k], a1);
        const float acc = (a0 + a1) + (a2 + a3);

        const int i = i0 + r;
        whtb[k * N + i] = __float2bfloat16(acc);   // transposed bf16 store

        float ps = acc * wa1;
        float pd = acc * wa2;
        #pragma unroll
        for (int mk = 1; mk < 16; mk <<= 1) {      // within 16-lane group
            ps += __shfl_xor(ps, mk);
            pd += __shfl_xor(pd, mk);
        }
        if (k == 0) {
            // |scores| small: exp() safe in f32; softmax shift-invariant.
            ws[AR_OFF + i] = __expf(ps);
            ws[CR_OFF + i] = __expf(ALPHA * ps);
            ws[BX_OFF + i] = __expf(pd);
            ws[DX_OFF + i] = __expf(ALPHA * pd);
        }
    }
}

// Kernel 2 (main): MFMA masked-softmax-weighted accumulation.
// Block = 512 threads / 8 waves sharing 16 output rows; per-wave disjoint
// 1024-col j-slice; depth-4 register ring; in-block reduce + ELU.
// At the adj-stream HBM roofline (round 6/10: ~42-46us cold==warm).
__global__ __launch_bounds__(512, 4) void gat_mfma_kernel(
    const int* __restrict__ adj, const float* __restrict__ ws,
    float* __restrict__ out)
{
    __shared__ float smem[16384];

    const int tid = threadIdx.x;     // 0..511
    const int i0 = blockIdx.x * BM;  // 16 rows per block

    #pragma unroll
    for (int u = 0; u < 4; ++u) {
        const int idx = u * 2048 + tid * 4;
        *(f32x4*)(smem + idx)        = *(const f32x4*)(ws + BX_OFF + idx);
        *(f32x4*)(smem + 8192 + idx) = *(const f32x4*)(ws + DX_OFF + idx);
    }
    __syncthreads();

    const int w    = tid >> 6;    // wave id = j-slice id
    const int lane = tid & 63;
    const int c15  = lane & 15;   // A-row (local), B-col, C-col
    const int g    = lane >> 4;   // k-group: this lane covers k = 8g..8g+7
    const int arow = i0 + c15;
    const int jc0  = w * WJ;

    const float Ar = ws[AR_OFF + arow];
    const float Cr = ws[CR_OFF + arow];

    const float* __restrict__ Bl = smem + jc0;
    const float* __restrict__ Dl = smem + 8192 + jc0;
    const unsigned short* __restrict__ whtb = (const unsigned short*)ws;
    const int* __restrict__ ap            = adj + (size_t)arow * N + jc0 + 8 * g;
    const unsigned short* __restrict__ wp = whtb + c15 * N + jc0 + 8 * g;

    f32x4 acc = {0.f, 0.f, 0.f, 0.f};
    float lsum = 0.f;

    i32x4 a0_0, a1_0, a0_1, a1_1, a0_2, a1_2, a0_3, a1_3;
    s16x8 fb_0, fb_1, fb_2, fb_3;

#define ISSUE(s, t) do {                                                       \
    const int off_ = 32 * (t);                                                 \
    a0_##s = *(const i32x4*)(ap + off_);                                       \
    a1_##s = *(const i32x4*)(ap + off_ + 4);                                   \
    fb_##s = *(const s16x8*)(wp + off_);                                       \
} while (0)

#define COMPUTE(s, t) do {                                                     \
    const int lb = (t) * 32 + 8 * g;                                           \
    const f32x4 B0 = *(const f32x4*)(Bl + lb);                                 \
    const f32x4 B1 = *(const f32x4*)(Bl + lb + 4);                             \
    const f32x4 D0 = *(const f32x4*)(Dl + lb);                                 \
    const f32x4 D1 = *(const f32x4*)(Dl + lb + 4);                             \
    float wf[8];                                                               \
    _Pragma("unroll") for (int e = 0; e < 4; ++e) {                            \
        const float ww = (a0_##s[e] > 0) ?                                     \
            fmaxf(Ar * B0[e], Cr * D0[e]) : 0.0f;                              \
        wf[e] = ww; lsum += ww;                                                \
    }                                                                          \
    _Pragma("unroll") for (int e = 0; e < 4; ++e) {                            \
        const float ww = (a1_##s[e] > 0) ?                                     \
            fmaxf(Ar * B1[e], Cr * D1[e]) : 0.0f;                              \
        wf[4 + e] = ww; lsum += ww;                                            \
    }                                                                          \
    s16x8 fa;                                                                  \
    _Pragma("unroll") for (int e = 0; e < 8; ++e)                              \
        fa[e] = (short)__builtin_bit_cast(unsigned short,                      \
                                          __float2bfloat16(wf[e]));           \
    acc = __builtin_amdgcn_mfma_f32_16x16x32_bf16(fa, fb_##s, acc, 0, 0, 0);   \
} while (0)

    ISSUE(0, 0); ISSUE(1, 1); ISSUE(2, 2); ISSUE(3, 3);

    #pragma unroll 1
    for (int t = 0; t < NT_T - 4; t += 4) {
        COMPUTE(0, t);     ISSUE(0, t + 4);
        COMPUTE(1, t + 1); ISSUE(1, t + 5);
        COMPUTE(2, t + 2); ISSUE(2, t + 6);
        COMPUTE(3, t + 3); ISSUE(3, t + 7);
    }
    COMPUTE(0, NT_T - 4); COMPUTE(1, NT_T - 3);
    COMPUTE(2, NT_T - 2); COMPUTE(3, NT_T - 1);
#undef ISSUE
#undef COMPUTE

    lsum += __shfl_xor(lsum, 16);
    lsum += __shfl_xor(lsum, 32);

    __syncthreads();
    #pragma unroll
    for (int r = 0; r < 4; ++r)
        smem[(w * 64 + lane) * 4 + r] = acc[r];
    if (g == 0)
        smem[2048 + w * 16 + c15] = lsum;
    __syncthreads();

    if (w == 0) {
        // C/D layout (m89-verified): col = lane&15, row = (lane>>4)*4 + reg
        float tot[4] = {0.f, 0.f, 0.f, 0.f};
        float den[4] = {0.f, 0.f, 0.f, 0.f};
        #pragma unroll
        for (int ww = 0; ww < NWAVE; ++ww) {
            #pragma unroll
            for (int r = 0; r < 4; ++r) {
                tot[r] += smem[(ww * 64 + lane) * 4 + r];
                den[r] += smem[2048 + ww * 16 + (4 * g + r)];
            }
        }
        #pragma unroll
        for (int r = 0; r < 4; ++r) {
            const float v = tot[r] / den[r];
            out[(i0 + 4 * g + r) * FOUT + c15] =
                (v > 0.0f) ? v : expm1f(v);   // ELU
        }
    }
}

extern "C" void kernel_launch(void* const* d_in, const int* in_sizes, int n_in,
                              void* d_out, int out_size, void* d_ws, size_t ws_size,
                              hipStream_t stream)
{
    const float* h    = (const float*)d_in[0];
    const int*   adj  = (const int*)d_in[1];
    const float* W    = (const float*)d_in[2];
    const float* attn = (const float*)d_in[3];
    float* out = (float*)d_out;
    float* ws  = (float*)d_ws;

    wh_score_kernel<<<N / RPRO, 256, 0, stream>>>(h, W, attn, ws);
    gat_mfma_kernel<<<N / BM, 512, 0, stream>>>(adj, ws, out);
}

// Round 13
// 59.172 us; speedup vs baseline: 2.5769x; 1.0034x over previous
//
#include <hip/hip_runtime.h>
#include <hip/hip_bf16.h>
#include <math.h>

#define N      8192
#define FIN    94
#define FOUT   16
#define ALPHA  0.2f
#define BM     16            // rows per block (main kernel)
#define WJ     1024          // j-columns per wave
#define NWAVE  8             // waves per block; NWAVE*WJ == N
#define NT_T   (WJ / 32)     // 32 col-tiles per wave
#define RPRO   32            // rows per prologue block

// ws layout: bf16 Wh_t[16][8192] at byte 0 (256 KB), then f32 tables.
#define AR_OFF 65536               // exp(s_src)
#define CR_OFF (AR_OFF + N)        // exp(0.2*s_src)
#define BX_OFF (AR_OFF + 2*N)      // exp(s_dst)
#define DX_OFF (AR_OFF + 3*N)      // exp(0.2*s_dst)

typedef int   i32x4 __attribute__((ext_vector_type(4)));
typedef float f32x4 __attribute__((ext_vector_type(4)));
typedef short s16x8 __attribute__((ext_vector_type(8)));

// Kernel 1 (prologue): Wh (bf16, transposed) + four exp tables.
// Block = 256 threads, 32 rows; h staged via coalesced f32x4 loads.
__global__ __launch_bounds__(256) void wh_score_kernel(
    const float* __restrict__ h, const float* __restrict__ W,
    const float* __restrict__ attn, float* __restrict__ ws)
{
    __shared__ float hl[RPRO * FIN];     // 32*94 = 3008 floats = 12 KB

    const int tid = threadIdx.x;
    const int i0 = blockIdx.x * RPRO;

    const float* hsrc = h + (size_t)i0 * FIN;
    #pragma unroll
    for (int u = 0; u < 3; ++u) {
        const int idx = (u * 256 + tid) * 4;
        if (idx < RPRO * FIN)
            *(f32x4*)(hl + idx) = *(const f32x4*)(hsrc + idx);
    }
    __syncthreads();

    const int k  = tid & 15;
    const int rr = tid >> 4;             // 0..15
    const float wa1 = attn[k];
    const float wa2 = attn[FOUT + k];
    __hip_bfloat16* whtb = (__hip_bfloat16*)ws;

    #pragma unroll
    for (int half = 0; half < 2; ++half) {
        const int r = rr + 16 * half;    // local row 0..31
        const float* hrow = hl + r * FIN;
        float a0 = 0.f, a1 = 0.f, a2 = 0.f, a3 = 0.f;
        #pragma unroll
        for (int c = 0; c < 92; c += 4) {
            a0 = fmaf(hrow[c],     W[c * FOUT + k],       a0);
            a1 = fmaf(hrow[c + 1], W[(c + 1) * FOUT + k], a1);
            a2 = fmaf(hrow[c + 2], W[(c + 2) * FOUT + k], a2);
            a3 = fmaf(hrow[c + 3], W[(c + 3) * FOUT + k], a3);
        }
        a0 = fmaf(hrow[92], W[92 * FOUT + k], a0);
        a1 = fmaf(hrow[93], W[93 * FOUT + k], a1);
        const float acc = (a0 + a1) + (a2 + a3);

        const int i = i0 + r;
        whtb[k * N + i] = __float2bfloat16(acc);   // transposed bf16 store

        float ps = acc * wa1;
        float pd = acc * wa2;
        #pragma unroll
        for (int mk = 1; mk < 16; mk <<= 1) {      // within 16-lane group
            ps += __shfl_xor(ps, mk);
            pd += __shfl_xor(pd, mk);
        }
        if (k == 0) {
            // |scores| small: exp() safe in f32; softmax shift-invariant.
            ws[AR_OFF + i] = __expf(ps);
            ws[CR_OFF + i] = __expf(ALPHA * ps);
            ws[BX_OFF + i] = __expf(pd);
            ws[DX_OFF + i] = __expf(ALPHA * pd);
        }
    }
}

// Kernel 2 (main): MFMA masked-softmax-weighted accumulation.
// Block = 512 threads / 8 waves sharing 16 output rows; per-wave disjoint
// 1024-col j-slice; depth-4 register ring; in-block reduce + ELU.
// Measured at the adj-stream memory floor (R10: warm == cold == 46.6us
// incl. gap; ideal 256MB @ 6.3TB/s = 42us).
__global__ __launch_bounds__(512, 4) void gat_mfma_kernel(
    const int* __restrict__ adj, const float* __restrict__ ws,
    float* __restrict__ out)
{
    __shared__ float smem[16384];

    const int tid = threadIdx.x;     // 0..511
    const int i0 = blockIdx.x * BM;  // 16 rows per block

    #pragma unroll
    for (int u = 0; u < 4; ++u) {
        const int idx = u * 2048 + tid * 4;
        *(f32x4*)(smem + idx)        = *(const f32x4*)(ws + BX_OFF + idx);
        *(f32x4*)(smem + 8192 + idx) = *(const f32x4*)(ws + DX_OFF + idx);
    }
    __syncthreads();

    const int w    = tid >> 6;    // wave id = j-slice id
    const int lane = tid & 63;
    const int c15  = lane & 15;   // A-row (local), B-col, C-col
    const int g    = lane >> 4;   // k-group: this lane covers k = 8g..8g+7
    const int arow = i0 + c15;
    const int jc0  = w * WJ;

    const float Ar = ws[AR_OFF + arow];
    const float Cr = ws[CR_OFF + arow];

    const float* __restrict__ Bl = smem + jc0;
    const float* __restrict__ Dl = smem + 8192 + jc0;
    const unsigned short* __restrict__ whtb = (const unsigned short*)ws;
    const int* __restrict__ ap            = adj + (size_t)arow * N + jc0 + 8 * g;
    const unsigned short* __restrict__ wp = whtb + c15 * N + jc0 + 8 * g;

    f32x4 acc = {0.f, 0.f, 0.f, 0.f};
    float lsum = 0.f;

    i32x4 a0_0, a1_0, a0_1, a1_1, a0_2, a1_2, a0_3, a1_3;
    s16x8 fb_0, fb_1, fb_2, fb_3;

#define ISSUE(s, t) do {                                                       \
    const int off_ = 32 * (t);                                                 \
    a0_##s = *(const i32x4*)(ap + off_);                                       \
    a1_##s = *(const i32x4*)(ap + off_ + 4);                                   \
    fb_##s = *(const s16x8*)(wp + off_);                                       \
} while (0)

#define COMPUTE(s, t) do {                                                     \
    const int lb = (t) * 32 + 8 * g;                                           \
    const f32x4 B0 = *(const f32x4*)(Bl + lb);                                 \
    const f32x4 B1 = *(const f32x4*)(Bl + lb + 4);                             \
    const f32x4 D0 = *(const f32x4*)(Dl + lb);                                 \
    const f32x4 D1 = *(const f32x4*)(Dl + lb + 4);                             \
    float wf[8];                                                               \
    _Pragma("unroll") for (int e = 0; e < 4; ++e) {                            \
        const float ww = (a0_##s[e] > 0) ?                                     \
            fmaxf(Ar * B0[e], Cr * D0[e]) : 0.0f;                              \
        wf[e] = ww; lsum += ww;                                                \
    }                                                                          \
    _Pragma("unroll") for (int e = 0; e < 4; ++e) {                            \
        const float ww = (a1_##s[e] > 0) ?                                     \
            fmaxf(Ar * B1[e], Cr * D1[e]) : 0.0f;                              \
        wf[4 + e] = ww; lsum += ww;                                            \
    }                                                                          \
    s16x8 fa;                                                                  \
    _Pragma("unroll") for (int e = 0; e < 8; ++e)                              \
        fa[e] = (short)__builtin_bit_cast(unsigned short,                      \
                                          __float2bfloat16(wf[e]));           \
    acc = __builtin_amdgcn_mfma_f32_16x16x32_bf16(fa, fb_##s, acc, 0, 0, 0);   \
} while (0)

    ISSUE(0, 0); ISSUE(1, 1); ISSUE(2, 2); ISSUE(3, 3);

    #pragma unroll 1
    for (int t = 0; t < NT_T - 4; t += 4) {
        COMPUTE(0, t);     ISSUE(0, t + 4);
        COMPUTE(1, t + 1); ISSUE(1, t + 5);
        COMPUTE(2, t + 2); ISSUE(2, t + 6);
        COMPUTE(3, t + 3); ISSUE(3, t + 7);
    }
    COMPUTE(0, NT_T - 4); COMPUTE(1, NT_T - 3);
    COMPUTE(2, NT_T - 2); COMPUTE(3, NT_T - 1);
#undef ISSUE
#undef COMPUTE

    lsum += __shfl_xor(lsum, 16);
    lsum += __shfl_xor(lsum, 32);

    __syncthreads();
    #pragma unroll
    for (int r = 0; r < 4; ++r)
        smem[(w * 64 + lane) * 4 + r] = acc[r];
    if (g == 0)
        smem[2048 + w * 16 + c15] = lsum;
    __syncthreads();

    if (w == 0) {
        // C/D layout (m89-verified): col = lane&15, row = (lane>>4)*4 + reg
        float tot[4] = {0.f, 0.f, 0.f, 0.f};
        float den[4] = {0.f, 0.f, 0.f, 0.f};
        #pragma unroll
        for (int ww = 0; ww < NWAVE; ++ww) {
            #pragma unroll
            for (int r = 0; r < 4; ++r) {
                tot[r] += smem[(ww * 64 + lane) * 4 + r];
                den[r] += smem[2048 + ww * 16 + (4 * g + r)];
            }
        }
        #pragma unroll
        for (int r = 0; r < 4; ++r) {
            const float v = tot[r] / den[r];
            out[(i0 + 4 * g + r) * FOUT + c15] =
                (v > 0.0f) ? v : expm1f(v);   // ELU
        }
    }
}

extern "C" void kernel_launch(void* const* d_in, const int* in_sizes, int n_in,
                              void* d_out, int out_size, void* d_ws, size_t ws_size,
                              hipStream_t stream)
{
    const float* h    = (const float*)d_in[0];
    const int*   adj  = (const int*)d_in[1];
    const float* W    = (const float*)d_in[2];
    const float* attn = (const float*)d_in[3];
    float* out = (float*)d_out;
    float* ws  = (float*)d_ws;

    wh_score_kernel<<<N / RPRO, 256, 0, stream>>>(h, W, attn, ws);
    gat_mfma_kernel<<<N / BM, 512, 0, stream>>>(adj, ws, out);
}